// Round 10
// baseline (1509.125 us; speedup 1.0000x reference)
//
#include <hip/hip_runtime.h>
#include <hip/hip_bf16.h>
#include <math.h>

#define B_ 8192
#define NN 32
#define TD 100
#define MD 172
#define KD 1376   // MD*8
#define TAUC 0.3f
#define LAMC 0.01f

typedef __attribute__((ext_vector_type(8))) short short8;
typedef __attribute__((ext_vector_type(4))) float f32x4;

#define WS_U_OFF    256
#define U_BYTES     ((size_t)B_ * KD * 2)
#define CONVB_ELEMS (11 * 43 * 64 * 8)     // 242688
#define WBIG_ELEMS  (22 * 7 * 64 * 8)      // 78848
#define ROOT_ELEMS  (11 * 9 * 64 * 8)      // 50688
#define CS2_ELEMS   (4 * 64 * 8)           // 2048: DFT twiddle A-frags
#define TBL_ELEMS   676                    // fr[100] c32[32] s32[32] Ct[256] St[256]
#define PREP_ITEMS  (CONVB_ELEMS + WBIG_ELEMS + ROOT_ELEMS + CS2_ELEMS + TBL_ELEMS)
#define MEAN_BLOCKS 1024
#define PREP_BLOCKS ((PREP_ITEMS + 255) / 256)

__device__ __forceinline__ float wred(float v) {
#pragma unroll
  for (int o = 32; o > 0; o >>= 1) v += __shfl_down(v, o, 64);
  return v;
}

__device__ __forceinline__ short bf16_bits(float f) {
  __hip_bfloat16 h = __float2bfloat16(f);
  return *(short*)&h;
}

__device__ __forceinline__ unsigned pack2(float a, float b) {
  return (unsigned)(unsigned short)bf16_bits(a) |
         ((unsigned)(unsigned short)bf16_bits(b) << 16);
}

// fast cos (revolutions + v_cos_f32); identical in all tfeat producers.
__device__ __forceinline__ float fcos(float x) {
  float r = x * 0.15915494309189535f;
  r = r - floorf(r);
  return __builtin_amdgcn_cosf(r);
}

// ---- Kernel 0: fused prep (blocks >= MEAN_BLOCKS) + Parseval mean (blocks < MEAN_BLOCKS) ----
__global__ __launch_bounds__(256) void k_pm(
    const int* __restrict__ nid, const float* __restrict__ t,
    const float* __restrict__ nt,
    const float* __restrict__ conv_w, const float* __restrict__ r1,
    const float* __restrict__ i1, const float* __restrict__ rhythm_w,
    const float* __restrict__ lin_w, short* __restrict__ convB,
    short* __restrict__ Wfrag, short* __restrict__ Rfrag,
    short* __restrict__ CS2frag, float* __restrict__ tbl,
    float* __restrict__ ws) {
  const float inv_s = 0.17677669529663687f;
  const int tid = threadIdx.x;
  if (blockIdx.x < MEAN_BLOCKS) {
    // Parseval global energy mean; fr computed inline (bit-identical formula)
    __shared__ float fr[TD];
    __shared__ float part[4];
    if (tid < TD) fr[tid] = (float)exp(-9.0 * (double)tid / 99.0 * 2.302585092994045684);
    __syncthreads();
    int idx = blockIdx.x * 256 + tid;
    int b = idx >> 5;
    float s = 0.f;
    if (nid[idx] != 0) {
      float dt = t[b] - nt[idx];
      for (int c = 0; c < TD; ++c) { float v = fcos(dt * fr[c]); s = fmaf(v, v, s); }
    }
    s = wred(s);
    if ((tid & 63) == 0) part[tid >> 6] = s;
    __syncthreads();
    if (tid == 0) atomicAdd(ws, part[0] + part[1] + part[2] + part[3]);
    return;
  }
  int idx = (blockIdx.x - MEAN_BLOCKS) * 256 + tid;
  if (idx < CONVB_ELEMS) {
    int j = idx & 7;
    int l = (idx >> 3) & 63;
    int s = (idx >> 9) % 43;
    int n0 = idx / (43 * 64 * 8);
    int k = s * 32 + (l >> 4) * 8 + j;
    int col = n0 * 16 + (l & 15);
    float v = (col < MD) ? conv_w[(long)col * KD + k] : 0.f;
    convB[idx] = bf16_bits(v);
    return;
  }
  idx -= CONVB_ELEMS;
  if (idx < WBIG_ELEMS) {
    int j = idx & 7;
    int l = (idx >> 3) & 63;
    int s = (idx % 3584) >> 9;
    int n0 = idx / 3584;
    int k = s * 32 + (l >> 4) * 8 + j;
    int col = n0 * 16 + (l & 15);
    float v = 0.f;
    if (k < 200) {
      if (n0 < 11) {
        int d = col;
        if (d < MD) v = (k < 100) ? r1[k * MD + d] : -i1[(k - 100) * MD + d];
      } else {
        int d = col - 176;
        if (d >= 0 && d < MD) v = (k < 100) ? i1[k * MD + d] : r1[(k - 100) * MD + d];
      }
    }
    Wfrag[idx] = bf16_bits(v);
    return;
  }
  idx -= WBIG_ELEMS;
  if (idx < ROOT_ELEMS) {
    int n = idx / 4608;
    int rem = idx % 4608;
    int s = rem >> 9;
    int l = (rem >> 3) & 63;
    int j = rem & 7;
    int k = s * 32 + (l >> 4) * 8 + j;
    int col = n * 16 + (l & 15);
    float v = 0.f;
    if (k < 272 && col < MD) {
      float hw = 0.5f * (rhythm_w[k * 4 + 1] + rhythm_w[k * 4 + 2]);
      v = hw * lin_w[k * MD + col];
    }
    Rfrag[idx] = bf16_bits(v);
    return;
  }
  idx -= ROOT_ELEMS;
  if (idx < CS2_ELEMS) {
    int set = idx >> 9, l = (idx >> 3) & 63, j = idx & 7;
    int mt = set >> 1, isS = set & 1;
    int kf = mt * 16 + (l & 15);
    int n = ((l >> 4) << 3) + j;
    double ang = 0.19634954084936207740 * (double)((kf * n) & 31);
    double v = isS ? -sin(ang) : cos(ang);
    CS2frag[idx] = bf16_bits((float)(v * 0.1767766952966368811));
    return;
  }
  idx -= CS2_ELEMS;
  if (idx < TBL_ELEMS) {
    float v;
    if (idx < 100)      v = (float)exp(-9.0 * (double)idx / 99.0 * 2.302585092994045684);
    else if (idx < 132) v = (float)cos(0.19634954084936207740 * (double)(idx - 100));
    else if (idx < 164) v = (float)sin(0.19634954084936207740 * (double)(idx - 132));
    else {
      // f32 Ct/St tables: Ct at [164..420), St at [420..676); row k2, col kp
      int i2 = idx - 164;
      int half = (i2 >= 256) ? 1 : 0;
      int r = i2 & 255;
      int k2 = r >> 5, kp = r & 31;
      int lo = k2 - 4; if (lo < 0) lo = 0;
      int hi = k2 + 28; if (hi > 31) hi = 31;
      double cs = 0.0, ss = 0.0;
      for (int n = lo; n <= hi; ++n) {
        double ang = 0.19634954084936207740 * (double)((kp * n) & 31);
        cs += cos(ang); ss += sin(ang);
      }
      v = (half ? (float)ss : (float)cs) * inv_s;
    }
    tbl[idx] = v;
  }
}

// ---- Kernel 2: per-b pipeline — MFMA DFT, fused filter+contraction, 4 barriers ----
__global__ __launch_bounds__(384, 8) void k_main(
    const int* __restrict__ nbr_id, const float* __restrict__ t,
    const float* __restrict__ nt, const float* __restrict__ rb1,
    const float* __restrict__ ib1, const float* __restrict__ ws0,
    const short* __restrict__ Wfrag, const short* __restrict__ CS2frag,
    const float* __restrict__ tbl, short* __restrict__ u_out) {
  __shared__ __align__(16) short sA[32 * 232];   // masked [Xr|Xi|pad] bf16
  __shared__ __align__(16) short sB[3584];       // tf B-frags: 7 tiles x 512
  __shared__ __align__(16) float s_cs[512];      // Ct[8][32] | St[8][32] f32
  __shared__ float s_fr[TD];
  __shared__ float s_dt[32], s_z[32], s_energy[32];

  const int tid = threadIdx.x;
  const int b = blockIdx.x;
  const int l = tid & 63, w = tid >> 6;
  const int c = l & 15, q = l >> 4;

  // P1: per-b neighbor meta + tables
  if (tid < 32) {
    int gi = b * NN + tid;
    int id = nbr_id[gi];
    float d = t[b] - nt[gi];
    s_z[tid]  = (id == 0) ? 0.f : 1.f;
    s_dt[tid] = (id == 0) ? 0.f : d;
    s_energy[tid] = 0.f;
  }
  if (tid < TD) s_fr[tid] = tbl[tid];
  for (int i = tid; i < 512; i += 384) s_cs[i] = tbl[164 + i];
  __syncthreads();

  // P2: tfeat bf16 directly into B-frag layout; zero sA pad cols 200..231
  for (int idx = tid; idx < 3584; idx += 384) {
    int tt = idx >> 9, ll = (idx >> 3) & 63, j = idx & 7;
    int n = ((ll >> 4) << 3) + j;
    int cc = (tt << 4) + (ll & 15);
    float v = (cc < TD) ? s_z[n] * fcos(s_dt[n] * s_fr[cc]) : 0.f;
    sB[idx] = bf16_bits(v);
  }
  if (tid < 256) {
    int row = tid >> 3, qq = tid & 7;
    *(uint2*)(sA + row * 232 + 200 + qq * 4) = make_uint2(0u, 0u);
  }
  __syncthreads();

  // P3: MFMA DFT — wave w: mside = w>=3, c-tiles {wn, wn+3, wn+6}
  const int mside = (w >= 3) ? 1 : 0;
  const int wn = w % 3;
  {
    short8 Ac = *(const short8*)(CS2frag + (((mside << 1) + 0) << 9) + (l << 3));
    short8 As = *(const short8*)(CS2frag + (((mside << 1) + 1) << 9) + (l << 3));
    float e4[4] = {0.f, 0.f, 0.f, 0.f};
    for (int tt = wn; tt < 7; tt += 3) {
      short8 Bt = *(const short8*)(sB + (tt << 9) + (l << 3));
      f32x4 xr = (f32x4)(0.f), xi = (f32x4)(0.f);
      xr = __builtin_amdgcn_mfma_f32_16x16x32_bf16(Ac, Bt, xr, 0, 0, 0);
      xi = __builtin_amdgcn_mfma_f32_16x16x32_bf16(As, Bt, xi, 0, 0, 0);
      int cc = (tt << 4) + c;
      if (cc < TD) {
#pragma unroll
        for (int r = 0; r < 4; ++r) {
          int k = mside * 16 + q * 4 + r;
          sA[k * 232 + cc]       = bf16_bits(xr[r]);
          sA[k * 232 + 100 + cc] = bf16_bits(xi[r]);
          e4[r] = fmaf(xr[r], xr[r], e4[r]);
          e4[r] = fmaf(xi[r], xi[r], e4[r]);
        }
      }
    }
#pragma unroll
    for (int m = 1; m < 16; m <<= 1) {
#pragma unroll
      for (int r = 0; r < 4; ++r) e4[r] += __shfl_xor(e4[r], m, 64);
    }
    if (c == 0) {
#pragma unroll
      for (int r = 0; r < 4; ++r)
        atomicAdd(&s_energy[mside * 16 + q * 4 + r], e4[r]);
    }
  }
  __syncthreads();

  // P5: zero rows failing the energy threshold
  {
    float gth = TAUC * (ws0[0] * (1.0f / 262144.0f) + 1e-6f);
    for (int idx = tid; idx < 800; idx += 384) {
      int row = idx / 25, qq = idx - row * 25;
      if (s_energy[row] < gth)
        *(uint4*)((char*)sA + row * 464 + qq * 16) = make_uint4(0u,0u,0u,0u);
    }
  }
  __syncthreads();

  // P6 fused: filter GEMM (both sides, both msides) + epilogue + ifft/conv
  // contraction per lane; u written directly. NO further barriers.
#pragma unroll
  for (int rep = 0; rep < 2; ++rep) {
    int n = w + 6 * rep;
    if (n < 11) {
      f32x4 aR0 = (f32x4)(0.f), aR1 = (f32x4)(0.f);
      f32x4 aI0 = (f32x4)(0.f), aI1 = (f32x4)(0.f);
#pragma unroll
      for (int s = 0; s < 7; ++s) {
        short8 br = *(const short8*)(Wfrag + (((n * 7 + s) << 6) + l) * 8);
        short8 bi = *(const short8*)(Wfrag + ((((n + 11) * 7 + s) << 6) + l) * 8);
        short8 a0 = *(const short8*)(sA + c * 232 + (q << 3) + s * 32);
        short8 a1 = *(const short8*)(sA + (16 + c) * 232 + (q << 3) + s * 32);
        aR0 = __builtin_amdgcn_mfma_f32_16x16x32_bf16(a0, br, aR0, 0, 0, 0);
        aR1 = __builtin_amdgcn_mfma_f32_16x16x32_bf16(a1, br, aR1, 0, 0, 0);
        aI0 = __builtin_amdgcn_mfma_f32_16x16x32_bf16(a0, bi, aI0, 0, 0, 0);
        aI1 = __builtin_amdgcn_mfma_f32_16x16x32_bf16(a1, bi, aI1, 0, 0, 0);
      }
      int d = n * 16 + c;
      bool valid = (d < MD);
      float br_ = valid ? rb1[d] : 0.f;
      float bi_ = valid ? ib1[d] : 0.f;
#pragma unroll
      for (int r = 0; r < 4; ++r) {
        aR0[r] = fmaxf(aR0[r] + br_ - LAMC, 0.f);
        aR1[r] = fmaxf(aR1[r] + br_ - LAMC, 0.f);
        aI0[r] = fmaxf(aI0[r] + bi_ - LAMC, 0.f);
        aI1[r] = fmaxf(aI1[r] + bi_ - LAMC, 0.f);
      }
      // contraction: u[k2][d] = sum_kp Ct[k2][kp]*yr[kp] - St[k2][kp]*yi[kp]
      // lane (q,c): kp = mside*16 + q*4 + r held in aR0/aR1 (yr), aI0/aI1 (yi)
      float uk[8];
#pragma unroll
      for (int k2 = 0; k2 < 8; ++k2) {
        f32x4 ct0 = *(const f32x4*)(s_cs + k2 * 32 + (q << 2));
        f32x4 ct1 = *(const f32x4*)(s_cs + k2 * 32 + 16 + (q << 2));
        f32x4 st0 = *(const f32x4*)(s_cs + 256 + k2 * 32 + (q << 2));
        f32x4 st1 = *(const f32x4*)(s_cs + 256 + k2 * 32 + 16 + (q << 2));
        float sacc = 0.f;
#pragma unroll
        for (int r = 0; r < 4; ++r) {
          sacc = fmaf(ct0[r],  aR0[r], sacc);
          sacc = fmaf(ct1[r],  aR1[r], sacc);
          sacc = fmaf(st0[r], -aI0[r], sacc);
          sacc = fmaf(st1[r], -aI1[r], sacc);
        }
        uk[k2] = sacc;
      }
#pragma unroll
      for (int k2 = 0; k2 < 8; ++k2) {
        uk[k2] += __shfl_xor(uk[k2], 16, 64);
        uk[k2] += __shfl_xor(uk[k2], 32, 64);
      }
      if (q == 0 && valid) {
        uint4 pv = make_uint4(pack2(uk[0], uk[1]), pack2(uk[2], uk[3]),
                              pack2(uk[4], uk[5]), pack2(uk[6], uk[7]));
        *(uint4*)(u_out + (long)b * KD + d * 8) = pv;
      }
    }
  }
}

// ---- Kernel 3: fused tail, 1024 thr: 11 conv waves + 5 root waves ----
__global__ __launch_bounds__(1024) void k_tail(
    const int* __restrict__ node_ids, const float* __restrict__ t,
    const float* __restrict__ node_mem, const short* __restrict__ u,
    const short* __restrict__ convB, const float* __restrict__ conv_b,
    const short* __restrict__ Rfrag, const float* __restrict__ lin_b,
    const float* __restrict__ mb_w, const float* __restrict__ mb_b,
    const float* __restrict__ ln_w, const float* __restrict__ ln_b,
    const float* __restrict__ tbl, float* __restrict__ out) {
  __shared__ __align__(16) short aR[16 * 296];
  __shared__ __align__(16) float Ct[16 * 176];
  const int tid = threadIdx.x;
  const int l = tid & 63, w = tid >> 6;
  const int c = l & 15, q = l >> 4;
  const int b0 = blockIdx.x * 16;

  for (int idx = tid; idx < 16 * 296; idx += 1024) {
    int r = idx / 296, cc = idx - r * 296;
    float v = 0.f;
    if (cc < TD) v = fcos(t[b0 + r] * tbl[cc]);
    else if (cc < 272) v = node_mem[(long)node_ids[b0 + r] * MD + (cc - TD)];
    aR[idx] = bf16_bits(v);
  }
  __syncthreads();

  f32x4 cacc = (f32x4)(0.f);
  if (w < 11) {
    const short* ap = u + (long)(b0 + c) * KD + (q << 3);
    const short* bp = convB + (((long)w * 43) * 64 + l) * 8;
#pragma unroll 4
    for (int s = 0; s < 43; ++s) {
      short8 a = *(const short8*)(ap + s * 32);
      short8 bb = *(const short8*)(bp + (s << 9));
      cacc = __builtin_amdgcn_mfma_f32_16x16x32_bf16(a, bb, cacc, 0, 0, 0);
    }
  } else {
    const int rstart = (w - 11) * 2;
    const int rcnt = (w == 15) ? 3 : 2;
    f32x4 racc[3];
#pragma unroll
    for (int tt = 0; tt < 3; ++tt) racc[tt] = (f32x4)(0.f);
    const short* arp = aR + c * 296 + (q << 3);
    for (int s = 0; s < 9; ++s) {
      short8 a = *(const short8*)(arp + s * 32);
#pragma unroll
      for (int tt = 0; tt < 3; ++tt) {
        if (tt < rcnt) {
          int n = rstart + tt;
          short8 bb = *(const short8*)(Rfrag + (((n * 9 + s) * 64) + l) * 8);
          racc[tt] = __builtin_amdgcn_mfma_f32_16x16x32_bf16(a, bb, racc[tt], 0, 0, 0);
        }
      }
    }
#pragma unroll
    for (int tt = 0; tt < 3; ++tt) {
      if (tt < rcnt) {
        int n = (rstart + tt) * 16 + c;
#pragma unroll
        for (int r = 0; r < 4; ++r)
          Ct[(q * 4 + r) * 176 + n] = racc[tt][r];
      }
    }
  }
  __syncthreads();

  if (tid < 256) {
    int r = tid >> 4, g = tid & 15;
    float v[11];
    float sm = 0.f, sq = 0.f;
#pragma unroll
    for (int j = 0; j < 11; ++j) {
      int cc = g + 16 * j;
      float x = (cc < MD) ? (Ct[r * 176 + cc] + lin_b[cc]) : 0.f;
      v[j] = x; sm += x; sq += x * x;
    }
#pragma unroll
    for (int m = 1; m < 16; m <<= 1) { sm += __shfl_xor(sm, m, 64); sq += __shfl_xor(sq, m, 64); }
    float mean = sm / 172.f;
    float rstd = rsqrtf(sq / 172.f - mean * mean + 1e-5f);
    float sm2 = 0.f, sq2 = 0.f;
#pragma unroll
    for (int j = 0; j < 11; ++j) {
      int cc = g + 16 * j;
      if (cc < MD) {
        float h = (v[j] - mean) * rstd * mb_w[cc] + mb_b[cc];
        v[j] = h; sm2 += h; sq2 += h * h;
      }
    }
#pragma unroll
    for (int m = 1; m < 16; m <<= 1) { sm2 += __shfl_xor(sm2, m, 64); sq2 += __shfl_xor(sq2, m, 64); }
    float mean2 = sm2 / 172.f;
    float rstd2 = rsqrtf(sq2 / 172.f - mean2 * mean2 + 1e-5f);
#pragma unroll
    for (int j = 0; j < 11; ++j) {
      int cc = g + 16 * j;
      if (cc < MD) Ct[r * 176 + cc] = (v[j] - mean2) * rstd2 * ln_w[cc] + ln_b[cc];
    }
  }
  __syncthreads();

  if (w < 11) {
    int n = w * 16 + c;
    if (n < MD) {
      float cb = conv_b[n];
#pragma unroll
      for (int r = 0; r < 4; ++r) {
        int mr = q * 4 + r;
        out[(long)(b0 + mr) * MD + n] =
            Ct[mr * 176 + n] + cacc[r] * (1.0f / 33.0f) + cb;
      }
    }
  }
}

extern "C" void kernel_launch(void* const* d_in, const int* in_sizes, int n_in,
                              void* d_out, int out_size, void* d_ws, size_t ws_size,
                              hipStream_t stream) {
  const int* node_ids = (const int*)d_in[0];
  const int* nbr_id   = (const int*)d_in[1];
  const float* t  = (const float*)d_in[2];
  const float* nt = (const float*)d_in[3];
  const float* node_mem = (const float*)d_in[4];
  const float* r1 = (const float*)d_in[5];
  const float* i1 = (const float*)d_in[6];
  const float* rb1 = (const float*)d_in[7];
  const float* ib1 = (const float*)d_in[8];
  const float* conv_w = (const float*)d_in[9];
  const float* conv_b = (const float*)d_in[10];
  const float* rhythm_w = (const float*)d_in[11];
  const float* lin_w = (const float*)d_in[12];
  const float* lin_b = (const float*)d_in[13];
  const float* mb_w = (const float*)d_in[14];
  const float* mb_b = (const float*)d_in[15];
  const float* ln_w = (const float*)d_in[16];
  const float* ln_b = (const float*)d_in[17];
  float* out = (float*)d_out;
  float* wsf = (float*)d_ws;

  char* base = (char*)d_ws;
  short* u       = (short*)(base + WS_U_OFF);
  short* convB   = (short*)(base + WS_U_OFF + U_BYTES);
  short* Wfrag   = convB + CONVB_ELEMS;
  short* Rfrag   = Wfrag + WBIG_ELEMS;
  short* CS2frag = Rfrag + ROOT_ELEMS;
  float* tbl     = (float*)(CS2frag + CS2_ELEMS);

  hipMemsetAsync(d_ws, 0, 16, stream);
  k_pm<<<MEAN_BLOCKS + PREP_BLOCKS, 256, 0, stream>>>(
      nbr_id, t, nt, conv_w, r1, i1, rhythm_w, lin_w,
      convB, Wfrag, Rfrag, CS2frag, tbl, wsf);
  k_main<<<B_, 384, 0, stream>>>(nbr_id, t, nt, rb1, ib1, wsf,
                                 Wfrag, CS2frag, tbl, u);
  k_tail<<<512, 1024, 0, stream>>>(node_ids, t, node_mem, u, convB, conv_b,
                                   Rfrag, lin_b, mb_w, mb_b, ln_w, ln_b, tbl, out);
}

// Round 11
// 931.913 us; speedup vs baseline: 1.6194x; 1.6194x over previous
//
#include <hip/hip_runtime.h>
#include <hip/hip_bf16.h>
#include <math.h>

#define B_ 8192
#define NN 32
#define TD 100
#define MD 172
#define KD 1376   // MD*8
#define TAUC 0.3f
#define LAMC 0.01f

typedef __attribute__((ext_vector_type(8))) short short8;
typedef __attribute__((ext_vector_type(4))) float f32x4;

#define WS_U_OFF    256
#define U_BYTES     ((size_t)B_ * KD * 2)
#define CONVB_ELEMS (11 * 43 * 64 * 8)     // 242688
#define WBIG_ELEMS  (22 * 7 * 64 * 8)      // 78848
#define ROOT_ELEMS  (11 * 9 * 64 * 8)      // 50688
#define CS2_ELEMS   (4 * 64 * 8)           // 2048: DFT twiddle A-frags
#define TBL_ELEMS   676                    // fr[100] c32[32] s32[32] Ct[256] St[256]
#define PREP_ITEMS  (CONVB_ELEMS + WBIG_ELEMS + ROOT_ELEMS + CS2_ELEMS + TBL_ELEMS)
#define MEAN_BLOCKS 1024
#define PREP_BLOCKS ((PREP_ITEMS + 255) / 256)

__device__ __forceinline__ float wred(float v) {
#pragma unroll
  for (int o = 32; o > 0; o >>= 1) v += __shfl_down(v, o, 64);
  return v;
}

__device__ __forceinline__ short bf16_bits(float f) {
  __hip_bfloat16 h = __float2bfloat16(f);
  return *(short*)&h;
}

__device__ __forceinline__ unsigned pack2(float a, float b) {
  return (unsigned)(unsigned short)bf16_bits(a) |
         ((unsigned)(unsigned short)bf16_bits(b) << 16);
}

// fast cos (revolutions + v_cos_f32); identical in all tfeat producers.
__device__ __forceinline__ float fcos(float x) {
  float r = x * 0.15915494309189535f;
  r = r - floorf(r);
  return __builtin_amdgcn_cosf(r);
}

// ---- Kernel 0: fused prep (blocks >= MEAN_BLOCKS) + Parseval mean ----
__global__ __launch_bounds__(256) void k_pm(
    const int* __restrict__ nid, const float* __restrict__ t,
    const float* __restrict__ nt,
    const float* __restrict__ conv_w, const float* __restrict__ r1,
    const float* __restrict__ i1, const float* __restrict__ rhythm_w,
    const float* __restrict__ lin_w, short* __restrict__ convB,
    short* __restrict__ Wfrag, short* __restrict__ Rfrag,
    short* __restrict__ CS2frag, float* __restrict__ tbl,
    float* __restrict__ ws) {
  const float inv_s = 0.17677669529663687f;
  const int tid = threadIdx.x;
  if (blockIdx.x < MEAN_BLOCKS) {
    __shared__ float fr[TD];
    __shared__ float part[4];
    if (tid < TD) fr[tid] = (float)exp(-9.0 * (double)tid / 99.0 * 2.302585092994045684);
    __syncthreads();
    int idx = blockIdx.x * 256 + tid;
    int b = idx >> 5;
    float s = 0.f;
    if (nid[idx] != 0) {
      float dt = t[b] - nt[idx];
      for (int c = 0; c < TD; ++c) { float v = fcos(dt * fr[c]); s = fmaf(v, v, s); }
    }
    s = wred(s);
    if ((tid & 63) == 0) part[tid >> 6] = s;
    __syncthreads();
    if (tid == 0) atomicAdd(ws, part[0] + part[1] + part[2] + part[3]);
    return;
  }
  int idx = (blockIdx.x - MEAN_BLOCKS) * 256 + tid;
  if (idx < CONVB_ELEMS) {
    int j = idx & 7;
    int l = (idx >> 3) & 63;
    int s = (idx >> 9) % 43;
    int n0 = idx / (43 * 64 * 8);
    int k = s * 32 + (l >> 4) * 8 + j;
    int col = n0 * 16 + (l & 15);
    float v = (col < MD) ? conv_w[(long)col * KD + k] : 0.f;
    convB[idx] = bf16_bits(v);
    return;
  }
  idx -= CONVB_ELEMS;
  if (idx < WBIG_ELEMS) {
    int j = idx & 7;
    int l = (idx >> 3) & 63;
    int s = (idx % 3584) >> 9;
    int n0 = idx / 3584;
    int k = s * 32 + (l >> 4) * 8 + j;
    int col = n0 * 16 + (l & 15);
    float v = 0.f;
    if (k < 200) {
      if (n0 < 11) {
        int d = col;
        if (d < MD) v = (k < 100) ? r1[k * MD + d] : -i1[(k - 100) * MD + d];
      } else {
        int d = col - 176;
        if (d >= 0 && d < MD) v = (k < 100) ? i1[k * MD + d] : r1[(k - 100) * MD + d];
      }
    }
    Wfrag[idx] = bf16_bits(v);
    return;
  }
  idx -= WBIG_ELEMS;
  if (idx < ROOT_ELEMS) {
    int n = idx / 4608;
    int rem = idx % 4608;
    int s = rem >> 9;
    int l = (rem >> 3) & 63;
    int j = rem & 7;
    int k = s * 32 + (l >> 4) * 8 + j;
    int col = n * 16 + (l & 15);
    float v = 0.f;
    if (k < 272 && col < MD) {
      float hw = 0.5f * (rhythm_w[k * 4 + 1] + rhythm_w[k * 4 + 2]);
      v = hw * lin_w[k * MD + col];
    }
    Rfrag[idx] = bf16_bits(v);
    return;
  }
  idx -= ROOT_ELEMS;
  if (idx < CS2_ELEMS) {
    int set = idx >> 9, l = (idx >> 3) & 63, j = idx & 7;
    int mt = set >> 1, isS = set & 1;
    int kf = mt * 16 + (l & 15);
    int n = ((l >> 4) << 3) + j;
    double ang = 0.19634954084936207740 * (double)((kf * n) & 31);
    double v = isS ? -sin(ang) : cos(ang);
    CS2frag[idx] = bf16_bits((float)(v * 0.1767766952966368811));
    return;
  }
  idx -= CS2_ELEMS;
  if (idx < TBL_ELEMS) {
    float v;
    if (idx < 100)      v = (float)exp(-9.0 * (double)idx / 99.0 * 2.302585092994045684);
    else if (idx < 132) v = (float)cos(0.19634954084936207740 * (double)(idx - 100));
    else if (idx < 164) v = (float)sin(0.19634954084936207740 * (double)(idx - 132));
    else {
      int i2 = idx - 164;
      int half = (i2 >= 256) ? 1 : 0;
      int r = i2 & 255;
      int k2 = r >> 5, kp = r & 31;
      int lo = k2 - 4; if (lo < 0) lo = 0;
      int hi = k2 + 28; if (hi > 31) hi = 31;
      double cs = 0.0, ss = 0.0;
      for (int n = lo; n <= hi; ++n) {
        double ang = 0.19634954084936207740 * (double)((kp * n) & 31);
        cs += cos(ang); ss += sin(ang);
      }
      v = (half ? (float)ss : (float)cs) * inv_s;
    }
    tbl[idx] = v;
  }
}

// ---- Kernel 2: per-b pipeline — MFMA DFT, register-disciplined fused P6 ----
__global__ __launch_bounds__(384, 8) void k_main(
    const int* __restrict__ nbr_id, const float* __restrict__ t,
    const float* __restrict__ nt, const float* __restrict__ rb1,
    const float* __restrict__ ib1, const float* __restrict__ ws0,
    const short* __restrict__ Wfrag, const short* __restrict__ CS2frag,
    const float* __restrict__ tbl, short* __restrict__ u_out) {
  __shared__ __align__(16) short sA[32 * 232];   // masked [Xr|Xi|pad] bf16
  __shared__ __align__(16) short sB[3584];       // tf B-frags: 7 tiles x 512
  __shared__ __align__(16) float s_cs[512];      // Ct[8][32] | St[8][32] f32
  __shared__ float s_fr[TD];
  __shared__ float s_dt[32], s_z[32], s_energy[32];

  const int tid = threadIdx.x;
  const int b = blockIdx.x;
  const int l = tid & 63, w = tid >> 6;
  const int c = l & 15, q = l >> 4;

  // P1: per-b neighbor meta + tables
  if (tid < 32) {
    int gi = b * NN + tid;
    int id = nbr_id[gi];
    float d = t[b] - nt[gi];
    s_z[tid]  = (id == 0) ? 0.f : 1.f;
    s_dt[tid] = (id == 0) ? 0.f : d;
    s_energy[tid] = 0.f;
  }
  if (tid < TD) s_fr[tid] = tbl[tid];
  for (int i = tid; i < 512; i += 384) s_cs[i] = tbl[164 + i];
  __syncthreads();

  // P2: tfeat bf16 directly into B-frag layout; zero sA pad cols 200..231
  for (int idx = tid; idx < 3584; idx += 384) {
    int tt = idx >> 9, ll = (idx >> 3) & 63, j = idx & 7;
    int n = ((ll >> 4) << 3) + j;
    int cc = (tt << 4) + (ll & 15);
    float v = (cc < TD) ? s_z[n] * fcos(s_dt[n] * s_fr[cc]) : 0.f;
    sB[idx] = bf16_bits(v);
  }
  if (tid < 256) {
    int row = tid >> 3, qq = tid & 7;
    *(uint2*)(sA + row * 232 + 200 + qq * 4) = make_uint2(0u, 0u);
  }
  __syncthreads();

  // P3: MFMA DFT — wave w: mside = w>=3, c-tiles {wn, wn+3, wn+6}
  const int mside = (w >= 3) ? 1 : 0;
  const int wn = w % 3;
  {
    short8 Ac = *(const short8*)(CS2frag + (((mside << 1) + 0) << 9) + (l << 3));
    short8 As = *(const short8*)(CS2frag + (((mside << 1) + 1) << 9) + (l << 3));
    float e4[4] = {0.f, 0.f, 0.f, 0.f};
    for (int tt = wn; tt < 7; tt += 3) {
      short8 Bt = *(const short8*)(sB + (tt << 9) + (l << 3));
      f32x4 xr = (f32x4)(0.f), xi = (f32x4)(0.f);
      xr = __builtin_amdgcn_mfma_f32_16x16x32_bf16(Ac, Bt, xr, 0, 0, 0);
      xi = __builtin_amdgcn_mfma_f32_16x16x32_bf16(As, Bt, xi, 0, 0, 0);
      int cc = (tt << 4) + c;
      if (cc < TD) {
#pragma unroll
        for (int r = 0; r < 4; ++r) {
          int k = mside * 16 + q * 4 + r;
          sA[k * 232 + cc]       = bf16_bits(xr[r]);
          sA[k * 232 + 100 + cc] = bf16_bits(xi[r]);
          e4[r] = fmaf(xr[r], xr[r], e4[r]);
          e4[r] = fmaf(xi[r], xi[r], e4[r]);
        }
      }
    }
#pragma unroll
    for (int m = 1; m < 16; m <<= 1) {
#pragma unroll
      for (int r = 0; r < 4; ++r) e4[r] += __shfl_xor(e4[r], m, 64);
    }
    if (c == 0) {
#pragma unroll
      for (int r = 0; r < 4; ++r)
        atomicAdd(&s_energy[mside * 16 + q * 4 + r], e4[r]);
    }
  }
  __syncthreads();

  // P5: zero rows failing the energy threshold
  {
    float gth = TAUC * (ws0[0] * (1.0f / 262144.0f) + 1e-6f);
    for (int idx = tid; idx < 800; idx += 384) {
      int row = idx / 25, qq = idx - row * 25;
      if (s_energy[row] < gth)
        *(uint4*)((char*)sA + row * 464 + qq * 16) = make_uint4(0u,0u,0u,0u);
    }
  }
  __syncthreads();

  // P6 fused, register-disciplined: per n-tile, side r then side i reusing
  // the same accumulators; uk[8] carries the contraction. No more barriers.
#pragma unroll 1
  for (int rep = 0; rep < 2; ++rep) {
    int n = w + 6 * rep;
    if (n >= 11) continue;
    const int d = n * 16 + c;
    const bool valid = (d < MD);
    float uk[8];
#pragma unroll
    for (int k2 = 0; k2 < 8; ++k2) uk[k2] = 0.f;

    // ---- side r ----
    {
      f32x4 acc0 = (f32x4)(0.f), acc1 = (f32x4)(0.f);
#pragma unroll 1
      for (int s = 0; s < 7; ++s) {
        short8 br = *(const short8*)(Wfrag + (((n * 7 + s) << 6) + l) * 8);
        short8 a0 = *(const short8*)(sA + c * 232 + (q << 3) + s * 32);
        short8 a1 = *(const short8*)(sA + (16 + c) * 232 + (q << 3) + s * 32);
        acc0 = __builtin_amdgcn_mfma_f32_16x16x32_bf16(a0, br, acc0, 0, 0, 0);
        acc1 = __builtin_amdgcn_mfma_f32_16x16x32_bf16(a1, br, acc1, 0, 0, 0);
      }
      float br_ = valid ? rb1[d] : 0.f;
#pragma unroll
      for (int r = 0; r < 4; ++r) {
        acc0[r] = fmaxf(acc0[r] + br_ - LAMC, 0.f);
        acc1[r] = fmaxf(acc1[r] + br_ - LAMC, 0.f);
      }
#pragma unroll
      for (int k2 = 0; k2 < 8; ++k2) {
        float sacc = uk[k2];
#pragma unroll
        for (int r = 0; r < 4; ++r) {
          sacc = fmaf(s_cs[k2 * 32 + (q << 2) + r],      acc0[r], sacc);
          sacc = fmaf(s_cs[k2 * 32 + 16 + (q << 2) + r], acc1[r], sacc);
        }
        uk[k2] = sacc;
      }
    }
    // ---- side i ----
    {
      f32x4 acc0 = (f32x4)(0.f), acc1 = (f32x4)(0.f);
#pragma unroll 1
      for (int s = 0; s < 7; ++s) {
        short8 bi = *(const short8*)(Wfrag + ((((n + 11) * 7 + s) << 6) + l) * 8);
        short8 a0 = *(const short8*)(sA + c * 232 + (q << 3) + s * 32);
        short8 a1 = *(const short8*)(sA + (16 + c) * 232 + (q << 3) + s * 32);
        acc0 = __builtin_amdgcn_mfma_f32_16x16x32_bf16(a0, bi, acc0, 0, 0, 0);
        acc1 = __builtin_amdgcn_mfma_f32_16x16x32_bf16(a1, bi, acc1, 0, 0, 0);
      }
      float bi_ = valid ? ib1[d] : 0.f;
#pragma unroll
      for (int r = 0; r < 4; ++r) {
        acc0[r] = fmaxf(acc0[r] + bi_ - LAMC, 0.f);
        acc1[r] = fmaxf(acc1[r] + bi_ - LAMC, 0.f);
      }
#pragma unroll
      for (int k2 = 0; k2 < 8; ++k2) {
        float sacc = uk[k2];
#pragma unroll
        for (int r = 0; r < 4; ++r) {
          sacc = fmaf(s_cs[256 + k2 * 32 + (q << 2) + r],      -acc0[r], sacc);
          sacc = fmaf(s_cs[256 + k2 * 32 + 16 + (q << 2) + r], -acc1[r], sacc);
        }
        uk[k2] = sacc;
      }
    }
    // reduce across q-groups and store
#pragma unroll
    for (int k2 = 0; k2 < 8; ++k2) {
      uk[k2] += __shfl_xor(uk[k2], 16, 64);
      uk[k2] += __shfl_xor(uk[k2], 32, 64);
    }
    if (q == 0 && valid) {
      uint4 pv = make_uint4(pack2(uk[0], uk[1]), pack2(uk[2], uk[3]),
                            pack2(uk[4], uk[5]), pack2(uk[6], uk[7]));
      *(uint4*)(u_out + (long)b * KD + d * 8) = pv;
    }
  }
}

// ---- Kernel 3: fused tail, 1024 thr: 11 conv waves + 5 root waves ----
__global__ __launch_bounds__(1024) void k_tail(
    const int* __restrict__ node_ids, const float* __restrict__ t,
    const float* __restrict__ node_mem, const short* __restrict__ u,
    const short* __restrict__ convB, const float* __restrict__ conv_b,
    const short* __restrict__ Rfrag, const float* __restrict__ lin_b,
    const float* __restrict__ mb_w, const float* __restrict__ mb_b,
    const float* __restrict__ ln_w, const float* __restrict__ ln_b,
    const float* __restrict__ tbl, float* __restrict__ out) {
  __shared__ __align__(16) short aR[16 * 296];
  __shared__ __align__(16) float Ct[16 * 176];
  const int tid = threadIdx.x;
  const int l = tid & 63, w = tid >> 6;
  const int c = l & 15, q = l >> 4;
  const int b0 = blockIdx.x * 16;

  for (int idx = tid; idx < 16 * 296; idx += 1024) {
    int r = idx / 296, cc = idx - r * 296;
    float v = 0.f;
    if (cc < TD) v = fcos(t[b0 + r] * tbl[cc]);
    else if (cc < 272) v = node_mem[(long)node_ids[b0 + r] * MD + (cc - TD)];
    aR[idx] = bf16_bits(v);
  }
  __syncthreads();

  f32x4 cacc = (f32x4)(0.f);
  if (w < 11) {
    const short* ap = u + (long)(b0 + c) * KD + (q << 3);
    const short* bp = convB + (((long)w * 43) * 64 + l) * 8;
#pragma unroll 4
    for (int s = 0; s < 43; ++s) {
      short8 a = *(const short8*)(ap + s * 32);
      short8 bb = *(const short8*)(bp + (s << 9));
      cacc = __builtin_amdgcn_mfma_f32_16x16x32_bf16(a, bb, cacc, 0, 0, 0);
    }
  } else {
    const int rstart = (w - 11) * 2;
    const int rcnt = (w == 15) ? 3 : 2;
    f32x4 racc[3];
#pragma unroll
    for (int tt = 0; tt < 3; ++tt) racc[tt] = (f32x4)(0.f);
    const short* arp = aR + c * 296 + (q << 3);
    for (int s = 0; s < 9; ++s) {
      short8 a = *(const short8*)(arp + s * 32);
#pragma unroll
      for (int tt = 0; tt < 3; ++tt) {
        if (tt < rcnt) {
          int n = rstart + tt;
          short8 bb = *(const short8*)(Rfrag + (((n * 9 + s) * 64) + l) * 8);
          racc[tt] = __builtin_amdgcn_mfma_f32_16x16x32_bf16(a, bb, racc[tt], 0, 0, 0);
        }
      }
    }
#pragma unroll
    for (int tt = 0; tt < 3; ++tt) {
      if (tt < rcnt) {
        int n = (rstart + tt) * 16 + c;
#pragma unroll
        for (int r = 0; r < 4; ++r)
          Ct[(q * 4 + r) * 176 + n] = racc[tt][r];
      }
    }
  }
  __syncthreads();

  if (tid < 256) {
    int r = tid >> 4, g = tid & 15;
    float v[11];
    float sm = 0.f, sq = 0.f;
#pragma unroll
    for (int j = 0; j < 11; ++j) {
      int cc = g + 16 * j;
      float x = (cc < MD) ? (Ct[r * 176 + cc] + lin_b[cc]) : 0.f;
      v[j] = x; sm += x; sq += x * x;
    }
#pragma unroll
    for (int m = 1; m < 16; m <<= 1) { sm += __shfl_xor(sm, m, 64); sq += __shfl_xor(sq, m, 64); }
    float mean = sm / 172.f;
    float rstd = rsqrtf(sq / 172.f - mean * mean + 1e-5f);
    float sm2 = 0.f, sq2 = 0.f;
#pragma unroll
    for (int j = 0; j < 11; ++j) {
      int cc = g + 16 * j;
      if (cc < MD) {
        float h = (v[j] - mean) * rstd * mb_w[cc] + mb_b[cc];
        v[j] = h; sm2 += h; sq2 += h * h;
      }
    }
#pragma unroll
    for (int m = 1; m < 16; m <<= 1) { sm2 += __shfl_xor(sm2, m, 64); sq2 += __shfl_xor(sq2, m, 64); }
    float mean2 = sm2 / 172.f;
    float rstd2 = rsqrtf(sq2 / 172.f - mean2 * mean2 + 1e-5f);
#pragma unroll
    for (int j = 0; j < 11; ++j) {
      int cc = g + 16 * j;
      if (cc < MD) Ct[r * 176 + cc] = (v[j] - mean2) * rstd2 * ln_w[cc] + ln_b[cc];
    }
  }
  __syncthreads();

  if (w < 11) {
    int n = w * 16 + c;
    if (n < MD) {
      float cb = conv_b[n];
#pragma unroll
      for (int r = 0; r < 4; ++r) {
        int mr = q * 4 + r;
        out[(long)(b0 + mr) * MD + n] =
            Ct[mr * 176 + n] + cacc[r] * (1.0f / 33.0f) + cb;
      }
    }
  }
}

extern "C" void kernel_launch(void* const* d_in, const int* in_sizes, int n_in,
                              void* d_out, int out_size, void* d_ws, size_t ws_size,
                              hipStream_t stream) {
  const int* node_ids = (const int*)d_in[0];
  const int* nbr_id   = (const int*)d_in[1];
  const float* t  = (const float*)d_in[2];
  const float* nt = (const float*)d_in[3];
  const float* node_mem = (const float*)d_in[4];
  const float* r1 = (const float*)d_in[5];
  const float* i1 = (const float*)d_in[6];
  const float* rb1 = (const float*)d_in[7];
  const float* ib1 = (const float*)d_in[8];
  const float* conv_w = (const float*)d_in[9];
  const float* conv_b = (const float*)d_in[10];
  const float* rhythm_w = (const float*)d_in[11];
  const float* lin_w = (const float*)d_in[12];
  const float* lin_b = (const float*)d_in[13];
  const float* mb_w = (const float*)d_in[14];
  const float* mb_b = (const float*)d_in[15];
  const float* ln_w = (const float*)d_in[16];
  const float* ln_b = (const float*)d_in[17];
  float* out = (float*)d_out;
  float* wsf = (float*)d_ws;

  char* base = (char*)d_ws;
  short* u       = (short*)(base + WS_U_OFF);
  short* convB   = (short*)(base + WS_U_OFF + U_BYTES);
  short* Wfrag   = convB + CONVB_ELEMS;
  short* Rfrag   = Wfrag + WBIG_ELEMS;
  short* CS2frag = Rfrag + ROOT_ELEMS;
  float* tbl     = (float*)(CS2frag + CS2_ELEMS);

  hipMemsetAsync(d_ws, 0, 16, stream);
  k_pm<<<MEAN_BLOCKS + PREP_BLOCKS, 256, 0, stream>>>(
      nbr_id, t, nt, conv_w, r1, i1, rhythm_w, lin_w,
      convB, Wfrag, Rfrag, CS2frag, tbl, wsf);
  k_main<<<B_, 384, 0, stream>>>(nbr_id, t, nt, rb1, ib1, wsf,
                                 Wfrag, CS2frag, tbl, u);
  k_tail<<<512, 1024, 0, stream>>>(node_ids, t, node_mem, u, convB, conv_b,
                                   Rfrag, lin_b, mb_w, mb_b, ln_w, ln_b, tbl, out);
}

// Round 12
// 554.792 us; speedup vs baseline: 2.7202x; 1.6798x over previous
//
#include <hip/hip_runtime.h>
#include <hip/hip_bf16.h>
#include <math.h>

#define B_ 8192
#define NN 32
#define TD 100
#define MD 172
#define KD 1376   // MD*8
#define TAUC 0.3f
#define LAMC 0.01f

typedef __attribute__((ext_vector_type(8))) short short8;
typedef __attribute__((ext_vector_type(4))) float f32x4;

#define WS_U_OFF    256
#define U_BYTES     ((size_t)B_ * KD * 2)
#define CONVB_ELEMS (11 * 43 * 64 * 8)     // 242688
#define WBIG_ELEMS  (22 * 7 * 64 * 8)      // 78848
#define CS_ELEMS    (2 * 64 * 8)           // 1024: ifft/conv CS B-op A-frags
#define ROOT_ELEMS  (11 * 9 * 64 * 8)      // 50688
#define CS2_ELEMS   (4 * 64 * 8)           // 2048: DFT twiddle A-frags
#define TBL_ELEMS   164                    // fr[100] c32[32] s32[32]
#define PREP_ITEMS  (CONVB_ELEMS + WBIG_ELEMS + CS_ELEMS + ROOT_ELEMS + CS2_ELEMS + TBL_ELEMS)
#define MEAN_BLOCKS 1024
#define PREP_BLOCKS ((PREP_ITEMS + 255) / 256)

__device__ __forceinline__ float wred(float v) {
#pragma unroll
  for (int o = 32; o > 0; o >>= 1) v += __shfl_down(v, o, 64);
  return v;
}

__device__ __forceinline__ short bf16_bits(float f) {
  __hip_bfloat16 h = __float2bfloat16(f);
  return *(short*)&h;
}

__device__ __forceinline__ unsigned pack2(float a, float b) {
  return (unsigned)(unsigned short)bf16_bits(a) |
         ((unsigned)(unsigned short)bf16_bits(b) << 16);
}

// fast cos (revolutions + v_cos_f32); identical in all tfeat producers.
__device__ __forceinline__ float fcos(float x) {
  float r = x * 0.15915494309189535f;
  r = r - floorf(r);
  return __builtin_amdgcn_cosf(r);
}

// ---- Kernel 0: Parseval mean (blocks < MEAN_BLOCKS) + all prep tables ----
__global__ __launch_bounds__(256) void k_pm(
    const int* __restrict__ nid, const float* __restrict__ t,
    const float* __restrict__ nt,
    const float* __restrict__ conv_w, const float* __restrict__ r1,
    const float* __restrict__ i1, const float* __restrict__ rhythm_w,
    const float* __restrict__ lin_w, short* __restrict__ convB,
    short* __restrict__ Wfrag, short* __restrict__ CSfrag,
    short* __restrict__ Rfrag, short* __restrict__ CS2frag,
    float* __restrict__ tbl, float* __restrict__ ws) {
  const float inv_s = 0.17677669529663687f;
  const int tid = threadIdx.x;
  if (blockIdx.x < MEAN_BLOCKS) {
    __shared__ float fr[TD];
    __shared__ float part[4];
    if (tid < TD) fr[tid] = (float)exp(-9.0 * (double)tid / 99.0 * 2.302585092994045684);
    __syncthreads();
    int idx = blockIdx.x * 256 + tid;
    int b = idx >> 5;
    float s = 0.f;
    if (nid[idx] != 0) {
      float dt = t[b] - nt[idx];
      for (int c = 0; c < TD; ++c) { float v = fcos(dt * fr[c]); s = fmaf(v, v, s); }
    }
    s = wred(s);
    if ((tid & 63) == 0) part[tid >> 6] = s;
    __syncthreads();
    if (tid == 0) atomicAdd(ws, part[0] + part[1] + part[2] + part[3]);
    return;
  }
  int idx = (blockIdx.x - MEAN_BLOCKS) * 256 + tid;
  if (idx < CONVB_ELEMS) {
    int j = idx & 7;
    int l = (idx >> 3) & 63;
    int s = (idx >> 9) % 43;
    int n0 = idx / (43 * 64 * 8);
    int k = s * 32 + (l >> 4) * 8 + j;
    int col = n0 * 16 + (l & 15);
    float v = (col < MD) ? conv_w[(long)col * KD + k] : 0.f;
    convB[idx] = bf16_bits(v);
    return;
  }
  idx -= CONVB_ELEMS;
  if (idx < WBIG_ELEMS) {
    int j = idx & 7;
    int l = (idx >> 3) & 63;
    int s = (idx % 3584) >> 9;
    int n0 = idx / 3584;
    int k = s * 32 + (l >> 4) * 8 + j;
    int col = n0 * 16 + (l & 15);
    float v = 0.f;
    if (k < 200) {
      if (n0 < 11) {
        int d = col;
        if (d < MD) v = (k < 100) ? r1[k * MD + d] : -i1[(k - 100) * MD + d];
      } else {
        int d = col - 176;
        if (d >= 0 && d < MD) v = (k < 100) ? i1[k * MD + d] : r1[(k - 100) * MD + d];
      }
    }
    Wfrag[idx] = bf16_bits(v);
    return;
  }
  idx -= WBIG_ELEMS;
  if (idx < CS_ELEMS) {
    int j = idx & 7;
    int l = (idx >> 3) & 63;
    int s = idx >> 9;
    int row = l & 15;
    int kq = s * 32 + (l >> 4) * 8 + j;
    float v = 0.f;
    if (row < 8) {
      int kp = (kq < 32) ? kq : kq - 32;
      int lo = row - 4; if (lo < 0) lo = 0;
      int hi = row + 28; if (hi > 31) hi = 31;
      double cs = 0.0, ss = 0.0;
      for (int n = lo; n <= hi; ++n) {
        double ang = 0.19634954084936207740 * (double)((kp * n) & 31);
        cs += cos(ang); ss += sin(ang);
      }
      v = ((kq < 32) ? (float)cs : -(float)ss) * inv_s;
    }
    CSfrag[idx] = bf16_bits(v);
    return;
  }
  idx -= CS_ELEMS;
  if (idx < ROOT_ELEMS) {
    int n = idx / 4608;
    int rem = idx % 4608;
    int s = rem >> 9;
    int l = (rem >> 3) & 63;
    int j = rem & 7;
    int k = s * 32 + (l >> 4) * 8 + j;
    int col = n * 16 + (l & 15);
    float v = 0.f;
    if (k < 272 && col < MD) {
      float hw = 0.5f * (rhythm_w[k * 4 + 1] + rhythm_w[k * 4 + 2]);
      v = hw * lin_w[k * MD + col];
    }
    Rfrag[idx] = bf16_bits(v);
    return;
  }
  idx -= ROOT_ELEMS;
  if (idx < CS2_ELEMS) {
    int set = idx >> 9, l = (idx >> 3) & 63, j = idx & 7;
    int mt = set >> 1, isS = set & 1;
    int kf = mt * 16 + (l & 15);
    int n = ((l >> 4) << 3) + j;
    double ang = 0.19634954084936207740 * (double)((kf * n) & 31);
    double v = isS ? -sin(ang) : cos(ang);
    CS2frag[idx] = bf16_bits((float)(v * 0.1767766952966368811));
    return;
  }
  idx -= CS2_ELEMS;
  if (idx < TBL_ELEMS) {
    float v;
    if (idx < 100)      v = (float)exp(-9.0 * (double)idx / 99.0 * 2.302585092994045684);
    else if (idx < 132) v = (float)cos(0.19634954084936207740 * (double)(idx - 100));
    else                v = (float)sin(0.19634954084936207740 * (double)(idx - 132));
    tbl[idx] = v;
  }
}

// ---- Kernel 2: per-b neighbor pipeline (R9-exact: MFMA DFT + Y roundtrip) ----
__global__ __launch_bounds__(384, 8) void k_main(
    const int* __restrict__ nbr_id, const float* __restrict__ t,
    const float* __restrict__ nt, const float* __restrict__ rb1,
    const float* __restrict__ ib1, const float* __restrict__ ws0,
    const short* __restrict__ Wfrag, const short* __restrict__ CSfrag,
    const short* __restrict__ CS2frag, const float* __restrict__ tbl,
    short* __restrict__ u_out) {
  __shared__ __align__(16) short sA[32 * 232];           // masked [Xr|Xi|pad] bf16
  __shared__ __align__(16) unsigned char s_un[12800];    // tf B-frags -> Y bf16 [176][32]
  __shared__ float s_fr[TD];
  __shared__ float s_dt[32], s_z[32];
  __shared__ float s_energy[32];

  short* sB = (short*)s_un;   // tf B-frags: 7 tiles x 512 shorts
  short* Y = (short*)s_un;
  const int tid = threadIdx.x;
  const int b = blockIdx.x;
  const int l = tid & 63, w = tid >> 6;
  const int c = l & 15, q = l >> 4;

  // P1: per-b neighbor meta + tables
  if (tid < 32) {
    int gi = b * NN + tid;
    int id = nbr_id[gi];
    float d = t[b] - nt[gi];
    s_z[tid]  = (id == 0) ? 0.f : 1.f;
    s_dt[tid] = (id == 0) ? 0.f : d;
    s_energy[tid] = 0.f;
  }
  if (tid < TD) s_fr[tid] = tbl[tid];
  __syncthreads();

  // P2: tfeat bf16 directly into B-frag layout; zero sA pad cols 200..231
  for (int idx = tid; idx < 3584; idx += 384) {
    int tt = idx >> 9, ll = (idx >> 3) & 63, j = idx & 7;
    int n = ((ll >> 4) << 3) + j;
    int cc = (tt << 4) + (ll & 15);
    float v = (cc < TD) ? s_z[n] * fcos(s_dt[n] * s_fr[cc]) : 0.f;
    sB[idx] = bf16_bits(v);
  }
  if (tid < 256) {
    int row = tid >> 3, qq = tid & 7;
    *(uint2*)(sA + row * 232 + 200 + qq * 4) = make_uint2(0u, 0u);
  }
  __syncthreads();

  // P3: MFMA DFT — wave w: mside = w>=3, c-tiles {wn, wn+3, wn+6}
  const int mside = (w >= 3) ? 1 : 0;
  const int wn = w % 3;
  {
    short8 Ac = *(const short8*)(CS2frag + (((mside << 1) + 0) << 9) + (l << 3));
    short8 As = *(const short8*)(CS2frag + (((mside << 1) + 1) << 9) + (l << 3));
    float e4[4] = {0.f, 0.f, 0.f, 0.f};
    for (int tt = wn; tt < 7; tt += 3) {
      short8 Bt = *(const short8*)(sB + (tt << 9) + (l << 3));
      f32x4 xr = (f32x4)(0.f), xi = (f32x4)(0.f);
      xr = __builtin_amdgcn_mfma_f32_16x16x32_bf16(Ac, Bt, xr, 0, 0, 0);
      xi = __builtin_amdgcn_mfma_f32_16x16x32_bf16(As, Bt, xi, 0, 0, 0);
      int cc = (tt << 4) + c;
      if (cc < TD) {
#pragma unroll
        for (int r = 0; r < 4; ++r) {
          int k = mside * 16 + q * 4 + r;
          sA[k * 232 + cc]       = bf16_bits(xr[r]);
          sA[k * 232 + 100 + cc] = bf16_bits(xi[r]);
          e4[r] = fmaf(xr[r], xr[r], e4[r]);
          e4[r] = fmaf(xi[r], xi[r], e4[r]);
        }
      }
    }
#pragma unroll
    for (int m = 1; m < 16; m <<= 1) {
#pragma unroll
      for (int r = 0; r < 4; ++r) e4[r] += __shfl_xor(e4[r], m, 64);
    }
    if (c == 0) {
#pragma unroll
      for (int r = 0; r < 4; ++r)
        atomicAdd(&s_energy[mside * 16 + q * 4 + r], e4[r]);
    }
  }
  __syncthreads();

  // P5: zero rows failing the energy threshold
  {
    float gth = TAUC * (ws0[0] * (1.0f / 262144.0f) + 1e-6f);
    for (int idx = tid; idx < 800; idx += 384) {
      int row = idx / 25, qq = idx - row * 25;
      if (s_energy[row] < gth)
        *(uint4*)((char*)sA + row * 464 + qq * 16) = make_uint4(0u,0u,0u,0u);
    }
  }
  __syncthreads();

  // P6a: side 0 (O_r); wave w owns n ∈ {w, w+6}; BOTH msides; A from LDS;
  // each Wfrag B-frag read ONCE per block.
#pragma unroll
  for (int rep = 0; rep < 2; ++rep) {
    int n = w + 6 * rep;
    if (n < 11) {
      f32x4 acc0 = (f32x4)(0.f), acc1 = (f32x4)(0.f);
#pragma unroll
      for (int s = 0; s < 7; ++s) {
        short8 bb = *(const short8*)(Wfrag + (((n * 7 + s) << 6) + l) * 8);
        short8 a0 = *(const short8*)(sA + c * 232 + (q << 3) + s * 32);
        short8 a1 = *(const short8*)(sA + (16 + c) * 232 + (q << 3) + s * 32);
        acc0 = __builtin_amdgcn_mfma_f32_16x16x32_bf16(a0, bb, acc0, 0, 0, 0);
        acc1 = __builtin_amdgcn_mfma_f32_16x16x32_bf16(a1, bb, acc1, 0, 0, 0);
      }
      int d = n * 16 + c;
      bool valid = (d < MD);
      float bias = valid ? rb1[d] : 0.f;
      f32x4 y0, y1;
#pragma unroll
      for (int r = 0; r < 4; ++r) {
        y0[r] = valid ? fmaxf(acc0[r] + bias - LAMC, 0.f) : 0.f;
        y1[r] = valid ? fmaxf(acc1[r] + bias - LAMC, 0.f) : 0.f;
      }
      *(uint2*)(Y + d * 32 + (q << 2))      = make_uint2(pack2(y0[0], y0[1]), pack2(y0[2], y0[3]));
      *(uint2*)(Y + d * 32 + 16 + (q << 2)) = make_uint2(pack2(y1[0], y1[1]), pack2(y1[2], y1[3]));
    }
  }
  __syncthreads();

  // P7a: u partial = CS_r @ Y_r
  f32x4 uacc[2];
  uacc[0] = (f32x4)(0.f); uacc[1] = (f32x4)(0.f);
  {
    short8 cs0 = *(const short8*)(CSfrag + (l << 3));
#pragma unroll
    for (int ti = 0; ti < 2; ++ti) {
      int nu = w + 6 * ti;
      if (nu < 11) {
        short8 bfr = *(const short8*)(Y + (nu * 16 + c) * 32 + (q << 3));
        uacc[ti] = __builtin_amdgcn_mfma_f32_16x16x32_bf16(cs0, bfr, uacc[ti], 0, 0, 0);
      }
    }
  }
  __syncthreads();

  // P6b: side 1 (O_i) overwrites Y; same single-read ownership
#pragma unroll
  for (int rep = 0; rep < 2; ++rep) {
    int n = w + 6 * rep;
    if (n < 11) {
      int nw = n + 11;
      f32x4 acc0 = (f32x4)(0.f), acc1 = (f32x4)(0.f);
#pragma unroll
      for (int s = 0; s < 7; ++s) {
        short8 bb = *(const short8*)(Wfrag + (((nw * 7 + s) << 6) + l) * 8);
        short8 a0 = *(const short8*)(sA + c * 232 + (q << 3) + s * 32);
        short8 a1 = *(const short8*)(sA + (16 + c) * 232 + (q << 3) + s * 32);
        acc0 = __builtin_amdgcn_mfma_f32_16x16x32_bf16(a0, bb, acc0, 0, 0, 0);
        acc1 = __builtin_amdgcn_mfma_f32_16x16x32_bf16(a1, bb, acc1, 0, 0, 0);
      }
      int d = n * 16 + c;
      bool valid = (d < MD);
      float bias = valid ? ib1[d] : 0.f;
      f32x4 y0, y1;
#pragma unroll
      for (int r = 0; r < 4; ++r) {
        y0[r] = valid ? fmaxf(acc0[r] + bias - LAMC, 0.f) : 0.f;
        y1[r] = valid ? fmaxf(acc1[r] + bias - LAMC, 0.f) : 0.f;
      }
      *(uint2*)(Y + d * 32 + (q << 2))      = make_uint2(pack2(y0[0], y0[1]), pack2(y0[2], y0[3]));
      *(uint2*)(Y + d * 32 + 16 + (q << 2)) = make_uint2(pack2(y1[0], y1[1]), pack2(y1[2], y1[3]));
    }
  }
  __syncthreads();

  // P7b: u += CS_i @ Y_i ; store u bf16 (kappa = d*8 + k2)
  {
    short8 cs1 = *(const short8*)(CSfrag + ((64 + l) << 3));
#pragma unroll
    for (int ti = 0; ti < 2; ++ti) {
      int nu = w + 6 * ti;
      if (nu < 11) {
        short8 bfr = *(const short8*)(Y + (nu * 16 + c) * 32 + (q << 3));
        uacc[ti] = __builtin_amdgcn_mfma_f32_16x16x32_bf16(cs1, bfr, uacc[ti], 0, 0, 0);
        int d = nu * 16 + c;
        if (q < 2 && d < MD) {
          uint2 pv = make_uint2(pack2(uacc[ti][0], uacc[ti][1]),
                                pack2(uacc[ti][2], uacc[ti][3]));
          *(uint2*)(u_out + (long)b * KD + d * 8 + q * 4) = pv;
        }
      }
    }
  }
}

// ---- Kernel 3: fused tail, 1024 thr: 11 conv waves + 5 root waves ----
__global__ __launch_bounds__(1024) void k_tail(
    const int* __restrict__ node_ids, const float* __restrict__ t,
    const float* __restrict__ node_mem, const short* __restrict__ u,
    const short* __restrict__ convB, const float* __restrict__ conv_b,
    const short* __restrict__ Rfrag, const float* __restrict__ lin_b,
    const float* __restrict__ mb_w, const float* __restrict__ mb_b,
    const float* __restrict__ ln_w, const float* __restrict__ ln_b,
    const float* __restrict__ tbl, float* __restrict__ out) {
  __shared__ __align__(16) short aR[16 * 296];
  __shared__ __align__(16) float Ct[16 * 176];
  const int tid = threadIdx.x;
  const int l = tid & 63, w = tid >> 6;
  const int c = l & 15, q = l >> 4;
  const int b0 = blockIdx.x * 16;

  for (int idx = tid; idx < 16 * 296; idx += 1024) {
    int r = idx / 296, cc = idx - r * 296;
    float v = 0.f;
    if (cc < TD) v = fcos(t[b0 + r] * tbl[cc]);
    else if (cc < 272) v = node_mem[(long)node_ids[b0 + r] * MD + (cc - TD)];
    aR[idx] = bf16_bits(v);
  }
  __syncthreads();

  f32x4 cacc = (f32x4)(0.f);
  if (w < 11) {
    const short* ap = u + (long)(b0 + c) * KD + (q << 3);
    const short* bp = convB + (((long)w * 43) * 64 + l) * 8;
#pragma unroll 4
    for (int s = 0; s < 43; ++s) {
      short8 a = *(const short8*)(ap + s * 32);
      short8 bb = *(const short8*)(bp + (s << 9));
      cacc = __builtin_amdgcn_mfma_f32_16x16x32_bf16(a, bb, cacc, 0, 0, 0);
    }
  } else {
    const int rstart = (w - 11) * 2;
    const int rcnt = (w == 15) ? 3 : 2;
    f32x4 racc[3];
#pragma unroll
    for (int tt = 0; tt < 3; ++tt) racc[tt] = (f32x4)(0.f);
    const short* arp = aR + c * 296 + (q << 3);
    for (int s = 0; s < 9; ++s) {
      short8 a = *(const short8*)(arp + s * 32);
#pragma unroll
      for (int tt = 0; tt < 3; ++tt) {
        if (tt < rcnt) {
          int n = rstart + tt;
          short8 bb = *(const short8*)(Rfrag + (((n * 9 + s) * 64) + l) * 8);
          racc[tt] = __builtin_amdgcn_mfma_f32_16x16x32_bf16(a, bb, racc[tt], 0, 0, 0);
        }
      }
    }
#pragma unroll
    for (int tt = 0; tt < 3; ++tt) {
      if (tt < rcnt) {
        int n = (rstart + tt) * 16 + c;
#pragma unroll
        for (int r = 0; r < 4; ++r)
          Ct[(q * 4 + r) * 176 + n] = racc[tt][r];
      }
    }
  }
  __syncthreads();

  if (tid < 256) {
    int r = tid >> 4, g = tid & 15;
    float v[11];
    float sm = 0.f, sq = 0.f;
#pragma unroll
    for (int j = 0; j < 11; ++j) {
      int cc = g + 16 * j;
      float x = (cc < MD) ? (Ct[r * 176 + cc] + lin_b[cc]) : 0.f;
      v[j] = x; sm += x; sq += x * x;
    }
#pragma unroll
    for (int m = 1; m < 16; m <<= 1) { sm += __shfl_xor(sm, m, 64); sq += __shfl_xor(sq, m, 64); }
    float mean = sm / 172.f;
    float rstd = rsqrtf(sq / 172.f - mean * mean + 1e-5f);
    float sm2 = 0.f, sq2 = 0.f;
#pragma unroll
    for (int j = 0; j < 11; ++j) {
      int cc = g + 16 * j;
      if (cc < MD) {
        float h = (v[j] - mean) * rstd * mb_w[cc] + mb_b[cc];
        v[j] = h; sm2 += h; sq2 += h * h;
      }
    }
#pragma unroll
    for (int m = 1; m < 16; m <<= 1) { sm2 += __shfl_xor(sm2, m, 64); sq2 += __shfl_xor(sq2, m, 64); }
    float mean2 = sm2 / 172.f;
    float rstd2 = rsqrtf(sq2 / 172.f - mean2 * mean2 + 1e-5f);
#pragma unroll
    for (int j = 0; j < 11; ++j) {
      int cc = g + 16 * j;
      if (cc < MD) Ct[r * 176 + cc] = (v[j] - mean2) * rstd2 * ln_w[cc] + ln_b[cc];
    }
  }
  __syncthreads();

  if (w < 11) {
    int n = w * 16 + c;
    if (n < MD) {
      float cb = conv_b[n];
#pragma unroll
      for (int r = 0; r < 4; ++r) {
        int mr = q * 4 + r;
        out[(long)(b0 + mr) * MD + n] =
            Ct[mr * 176 + n] + cacc[r] * (1.0f / 33.0f) + cb;
      }
    }
  }
}

extern "C" void kernel_launch(void* const* d_in, const int* in_sizes, int n_in,
                              void* d_out, int out_size, void* d_ws, size_t ws_size,
                              hipStream_t stream) {
  const int* node_ids = (const int*)d_in[0];
  const int* nbr_id   = (const int*)d_in[1];
  const float* t  = (const float*)d_in[2];
  const float* nt = (const float*)d_in[3];
  const float* node_mem = (const float*)d_in[4];
  const float* r1 = (const float*)d_in[5];
  const float* i1 = (const float*)d_in[6];
  const float* rb1 = (const float*)d_in[7];
  const float* ib1 = (const float*)d_in[8];
  const float* conv_w = (const float*)d_in[9];
  const float* conv_b = (const float*)d_in[10];
  const float* rhythm_w = (const float*)d_in[11];
  const float* lin_w = (const float*)d_in[12];
  const float* lin_b = (const float*)d_in[13];
  const float* mb_w = (const float*)d_in[14];
  const float* mb_b = (const float*)d_in[15];
  const float* ln_w = (const float*)d_in[16];
  const float* ln_b = (const float*)d_in[17];
  float* out = (float*)d_out;
  float* wsf = (float*)d_ws;

  char* base = (char*)d_ws;
  short* u       = (short*)(base + WS_U_OFF);
  short* convB   = (short*)(base + WS_U_OFF + U_BYTES);
  short* Wfrag   = convB + CONVB_ELEMS;
  short* CSfrag  = Wfrag + WBIG_ELEMS;
  short* Rfrag   = CSfrag + CS_ELEMS;
  short* CS2frag = Rfrag + ROOT_ELEMS;
  float* tbl     = (float*)(CS2frag + CS2_ELEMS);

  hipMemsetAsync(d_ws, 0, 16, stream);
  k_pm<<<MEAN_BLOCKS + PREP_BLOCKS, 256, 0, stream>>>(
      nbr_id, t, nt, conv_w, r1, i1, rhythm_w, lin_w,
      convB, Wfrag, CSfrag, Rfrag, CS2frag, tbl, wsf);
  k_main<<<B_, 384, 0, stream>>>(nbr_id, t, nt, rb1, ib1, wsf,
                                 Wfrag, CSfrag, CS2frag, tbl, u);
  k_tail<<<512, 1024, 0, stream>>>(node_ids, t, node_mem, u, convB, conv_b,
                                   Rfrag, lin_b, mb_w, mb_b, ln_w, ln_b, tbl, out);
}